// Round 11
// baseline (948.399 us; speedup 1.0000x reference)
//
#include <hip/hip_runtime.h>

// Round 8 (resubmit x3): + explicit register double-buffer for A-fragments.
// Per (kw,ks) step: issue next step's 8 A-loads BEFORE current step's MFMAs;
// cross-group A-prefetch issued before the barrier. B stays LDS-staged
// (double-buffered row groups), XCD-chunked swizzle kept.

#define XF 17
#define XH 128
#define XWD 128
#define XCS (XF * XH * XWD)      // 278528
#define OCS (33 * 256 * 256)
#define OFS (256 * 256)

typedef short short8 __attribute__((ext_vector_type(8)));
typedef float f32x4 __attribute__((ext_vector_type(4)));

__device__ inline unsigned short f2bf(float v) {
    union { float f; unsigned u; } c; c.f = v;
    unsigned r = c.u + 0x7FFFu + ((c.u >> 16) & 1u);
    return (unsigned short)(r >> 16);
}

__global__ __launch_bounds__(256) void prep_w(const float* __restrict__ Wf,
                                              unsigned short* __restrict__ Wb) {
    const int idx = blockIdx.x * 256 + threadIdx.x;     // tap*16384 + ch*64 + ic
    const int ic = idx & 63, ch = (idx >> 6) & 255, t = idx >> 14;
    Wb[idx] = f2bf(Wf[(ch * 64 + ic) * 27 + t]);
}

__global__ __launch_bounds__(256) void prep_x(const float* __restrict__ x,
                                              unsigned short* __restrict__ xT) {
    __shared__ unsigned short l[128][72];
    const int f = blockIdx.x >> 7, y = blockIdx.x & 127;
    const int tid = threadIdx.x;
    const int w = tid & 127;
#pragma unroll
    for (int rep = 0; rep < 32; ++rep) {
        const int ic = rep * 2 + (tid >> 7);
        l[w][ic] = f2bf(x[(size_t)ic * XCS + f * (XH * XWD) + y * XWD + w]);
    }
    __syncthreads();
    unsigned short* dst = xT + (size_t)(f * 128 + y) * 8192;
    const int icg = tid & 7;
#pragma unroll
    for (int rep = 0; rep < 4; ++rep) {
        const int ww = rep * 32 + (tid >> 3);
        *(short8*)(dst + ww * 64 + icg * 8) = *(const short8*)(&l[ww][icg * 8]);
    }
}

// issue 8 A-fragment loads for tap index `tap`, ks half `ksv`
#define LOAD_A(dst, tap, ksv)                                                 \
    {                                                                         \
        const unsigned short* _p = Wb + (size_t)(tap)*16384 + wmoff           \
                                   + (ksv)*32 + aoff;                         \
        _Pragma("unroll")                                                     \
        for (int mm = 0; mm < 8; ++mm)                                        \
            dst[mm] = *(const short8*)(_p + mm * 1024);                       \
    }

// ds_read 4 B-fragments for (kw,ks) from buffer cb, then 32 MFMAs (nn-outer)
#define STEP_MFMA(asrc, kwv, ksv, cbv)                                        \
    {                                                                         \
        short8 b0, b1, b2, b3;                                                \
        b0 = *(const short8*)(&lds[cbv][(wn * 64 + 0 * 16 + lr + (kwv)) * 72  \
                                        + (ksv)*32 + lg * 8]);                \
        b1 = *(const short8*)(&lds[cbv][(wn * 64 + 1 * 16 + lr + (kwv)) * 72  \
                                        + (ksv)*32 + lg * 8]);                \
        b2 = *(const short8*)(&lds[cbv][(wn * 64 + 2 * 16 + lr + (kwv)) * 72  \
                                        + (ksv)*32 + lg * 8]);                \
        b3 = *(const short8*)(&lds[cbv][(wn * 64 + 3 * 16 + lr + (kwv)) * 72  \
                                        + (ksv)*32 + lg * 8]);                \
        _Pragma("unroll")                                                     \
        for (int mm = 0; mm < 8; ++mm)                                        \
            acc[mm][0] = __builtin_amdgcn_mfma_f32_16x16x32_bf16(             \
                asrc[mm], b0, acc[mm][0], 0, 0, 0);                           \
        _Pragma("unroll")                                                     \
        for (int mm = 0; mm < 8; ++mm)                                        \
            acc[mm][1] = __builtin_amdgcn_mfma_f32_16x16x32_bf16(             \
                asrc[mm], b1, acc[mm][1], 0, 0, 0);                           \
        _Pragma("unroll")                                                     \
        for (int mm = 0; mm < 8; ++mm)                                        \
            acc[mm][2] = __builtin_amdgcn_mfma_f32_16x16x32_bf16(             \
                asrc[mm], b2, acc[mm][2], 0, 0, 0);                           \
        _Pragma("unroll")                                                     \
        for (int mm = 0; mm < 8; ++mm)                                        \
            acc[mm][3] = __builtin_amdgcn_mfma_f32_16x16x32_bf16(             \
                asrc[mm], b3, acc[mm][3], 0, 0, 0);                           \
    }

__global__ __launch_bounds__(256, 2) void conv_mfma(
    const float* __restrict__ x, const unsigned short* __restrict__ Wb,
    const float* __restrict__ bias, const unsigned short* __restrict__ xT,
    float* __restrict__ out)
{
    __shared__ unsigned short lds[2][9360];   // 2 x 130 rows x 72 shorts

    const int tid = threadIdx.x;
    const int lane = tid & 63, lr = lane & 15, lg = lane >> 4;
    const int wv = tid >> 6, wm = wv >> 1, wn = wv & 1;
    const int aoff = lr * 64 + lg * 8;        // per-lane A offset (shorts)
    const int wmoff = wm * 8192;

    const int bid = blockIdx.x;
    const int sbid = (bid & 7) * 272 + (bid >> 3);
    const int f = sbid >> 7, y = sbid & 127;

    const int kf0 = (f == 0) ? 1 : 0, kf1 = (f == XF - 1) ? 1 : 2;
    const int kh0 = (y == 0) ? 1 : 0, kh1 = (y == XH - 1) ? 1 : 2;

    if (tid < 36) {
        const int b = tid / 18, rr = (tid % 18) / 9, k = tid % 9;
        const short8 zz = {0, 0, 0, 0, 0, 0, 0, 0};
        *(short8*)(&lds[b][(rr ? 129 * 72 : 0) + k * 8]) = zz;
    }

    const int scol = 1 + (tid >> 1);
    const int sic  = (tid & 1) * 32;

    short8 aA[8], aB[8];
    // prefetch A for the first group's first step (kw=0,ks=0) — global, pre-barrier OK
    LOAD_A(aA, (kf0 * 3 + kh0) * 3 + 0, 0);

    // stage first B row-group into buffer 0
    {
        const unsigned short* s = xT + (size_t)((f + kf0 - 1) * 128 + (y + kh0 - 1)) * 8192
                                  + (tid >> 1) * 64 + sic;
        short8 v0 = *(const short8*)(s);
        short8 v1 = *(const short8*)(s + 8);
        short8 v2 = *(const short8*)(s + 16);
        short8 v3 = *(const short8*)(s + 24);
        unsigned short* d = &lds[0][scol * 72 + sic];
        *(short8*)(d) = v0; *(short8*)(d + 8) = v1;
        *(short8*)(d + 16) = v2; *(short8*)(d + 24) = v3;
    }
    __syncthreads();

    f32x4 acc[8][4];
#pragma unroll
    for (int mm = 0; mm < 8; ++mm)
#pragma unroll
        for (int nn = 0; nn < 4; ++nn) {
            f32x4 z = {0.f, 0.f, 0.f, 0.f};
            acc[mm][nn] = z;
        }

    int gi = 0;
#pragma unroll 1
    for (int kf = kf0; kf <= kf1; ++kf) {
#pragma unroll 1
        for (int kh = kh0; kh <= kh1; ++kh, ++gi) {
            const int cb = gi & 1;
            const int tap0 = (kf * 3 + kh) * 3;

            int nkf = kf, nkh = kh + 1;
            if (nkh > kh1) { nkf = kf + 1; nkh = kh0; }
            const bool hasNext = (nkf <= kf1);

            // issue next B row-group loads early (T14)
            short8 pf0, pf1, pf2, pf3;
            if (hasNext) {
                const unsigned short* s = xT
                    + (size_t)((f + nkf - 1) * 128 + (y + nkh - 1)) * 8192
                    + (tid >> 1) * 64 + sic;
                pf0 = *(const short8*)(s);
                pf1 = *(const short8*)(s + 8);
                pf2 = *(const short8*)(s + 16);
                pf3 = *(const short8*)(s + 24);
            }

            // 6 steps = (kw 0..2) x (ks 0..1), A double-buffered aA/aB
#pragma unroll
            for (int kw = 0; kw < 3; ++kw) {
                // even step (ks=0): consume aA, prefetch aB <- (kw, ks=1)
                LOAD_A(aB, tap0 + kw, 1);
                STEP_MFMA(aA, kw, 0, cb);
                // odd step (ks=1): consume aB, prefetch aA <- next
                if (kw < 2) {
                    LOAD_A(aA, tap0 + kw + 1, 0);
                } else {
                    if (hasNext) {
                        // write prefetched B row into other buffer, then
                        // prefetch next group's first A batch
                        unsigned short* d = &lds[cb ^ 1][scol * 72 + sic];
                        *(short8*)(d) = pf0; *(short8*)(d + 8) = pf1;
                        *(short8*)(d + 16) = pf2; *(short8*)(d + 24) = pf3;
                        LOAD_A(aA, (nkf * 3 + nkh) * 3, 0);
                    }
                }
                STEP_MFMA(aB, kw, 1, cb);
            }

            if (hasNext) __syncthreads();
        }
    }

    // epilogue: bias + shuffle scatter + skip (verified algebra)
#pragma unroll
    for (int mm = 0; mm < 8; ++mm) {
        const int chb = wm * 128 + mm * 16 + lg * 4;
#pragma unroll
        for (int nn = 0; nn < 4; ++nn) {
            const int wcol = wn * 64 + nn * 16 + lr;
#pragma unroll
            for (int r = 0; r < 4; ++r) {
                const int ch = chb + r;
                const float h = acc[mm][nn][r] + bias[ch];
                if (f == 0) {
                    if (ch & 32) continue;
                    const int p = ch >> 7, q = (ch >> 6) & 1, m = ch & 31;
                    const float sk = x[(size_t)((p * 64 + q * 32 + m) >> 1) * XCS
                                       + y * XWD + wcol];
                    out[(size_t)m * OCS + (size_t)(2 * y + p) * 256 + 2 * wcol + q]
                        = h + sk;
                } else {
                    const int aa = ch >> 7, p = (ch >> 6) & 1, q = (ch >> 5) & 1,
                              m = ch & 31;
                    const int fo = 1 + 2 * (f - 1) + aa;
                    const float sk = x[(size_t)(ch >> 2) * XCS
                                       + (size_t)f * (XH * XWD) + y * XWD + wcol];
                    out[(size_t)m * OCS + (size_t)fo * OFS
                        + (size_t)(2 * y + p) * 256 + 2 * wcol + q] = h + sk;
                }
            }
        }
    }
}

extern "C" void kernel_launch(void* const* d_in, const int* in_sizes, int n_in,
                              void* d_out, int out_size, void* d_ws, size_t ws_size,
                              hipStream_t stream) {
    const float* x  = (const float*)d_in[0];
    const float* Wf = (const float*)d_in[1];
    const float* b  = (const float*)d_in[2];
    float* out = (float*)d_out;

    unsigned short* Wb = (unsigned short*)d_ws;                         // 884,736 B
    unsigned short* xT = (unsigned short*)((char*)d_ws + (1 << 20));    // 35.65 MB

    prep_w<<<dim3(1728), dim3(256), 0, stream>>>(Wf, Wb);
    prep_x<<<dim3(17 * 128), dim3(256), 0, stream>>>(x, xT);
    conv_mfma<<<dim3(17 * 128), dim3(256), 0, stream>>>(x, Wb, b, xT, out);
}

// Round 12
// 900.893 us; speedup vs baseline: 1.0527x; 1.0527x over previous
//
#include <hip/hip_runtime.h>

// Round 12: occupancy fix. Split 256-ch tile across 2 blocks (chHalf) ->
// per-wave acc 4x4 (64 AGPR), __launch_bounds__(256,4) => 4 waves/SIMD.
// Structure otherwise = round-7 best (LDS-staged B + T14 prefetch + swizzle;
// NO manual A double-buffer — that regressed in round 11).

#define XF 17
#define XH 128
#define XWD 128
#define XCS (XF * XH * XWD)      // 278528
#define OCS (33 * 256 * 256)
#define OFS (256 * 256)

typedef short short8 __attribute__((ext_vector_type(8)));
typedef float f32x4 __attribute__((ext_vector_type(4)));

__device__ inline unsigned short f2bf(float v) {
    union { float f; unsigned u; } c; c.f = v;
    unsigned r = c.u + 0x7FFFu + ((c.u >> 16) & 1u);
    return (unsigned short)(r >> 16);
}

__global__ __launch_bounds__(256) void prep_w(const float* __restrict__ Wf,
                                              unsigned short* __restrict__ Wb) {
    const int idx = blockIdx.x * 256 + threadIdx.x;     // tap*16384 + ch*64 + ic
    const int ic = idx & 63, ch = (idx >> 6) & 255, t = idx >> 14;
    Wb[idx] = f2bf(Wf[(ch * 64 + ic) * 27 + t]);
}

__global__ __launch_bounds__(256) void prep_x(const float* __restrict__ x,
                                              unsigned short* __restrict__ xT) {
    __shared__ unsigned short l[128][72];
    const int f = blockIdx.x >> 7, y = blockIdx.x & 127;
    const int tid = threadIdx.x;
    const int w = tid & 127;
#pragma unroll
    for (int rep = 0; rep < 32; ++rep) {
        const int ic = rep * 2 + (tid >> 7);
        l[w][ic] = f2bf(x[(size_t)ic * XCS + f * (XH * XWD) + y * XWD + w]);
    }
    __syncthreads();
    unsigned short* dst = xT + (size_t)(f * 128 + y) * 8192;
    const int icg = tid & 7;
#pragma unroll
    for (int rep = 0; rep < 4; ++rep) {
        const int ww = rep * 32 + (tid >> 3);
        *(short8*)(dst + ww * 64 + icg * 8) = *(const short8*)(&l[ww][icg * 8]);
    }
}

// block = (f, y, chHalf); 4 waves = 2M(64ch) x 2N(64w); C-tile 128ch x 128w.
__global__ __launch_bounds__(256, 4) void conv_mfma(
    const float* __restrict__ x, const unsigned short* __restrict__ Wb,
    const float* __restrict__ bias, const unsigned short* __restrict__ xT,
    float* __restrict__ out)
{
    __shared__ unsigned short lds[2][9360];   // 2 x 130 rows x 72 shorts

    const int tid = threadIdx.x;
    const int lane = tid & 63, lr = lane & 15, lg = lane >> 4;
    const int wv = tid >> 6, wm = wv >> 1, wn = wv & 1;

    // bijective XCD-chunked swizzle: 4352 blocks = 8 XCDs x 544
    const int bid = blockIdx.x;
    const int sbid = (bid & 7) * 544 + (bid >> 3);
    const int chHalf = sbid & 1;
    const int y = (sbid >> 1) & 127;
    const int f = sbid >> 8;

    // per-lane A base: ch = chHalf*128 + wm*64 + mm*16 + lr
    const int wmoff = chHalf * 8192 + wm * 4096 + lr * 64 + lg * 8;

    const int kf0 = (f == 0) ? 1 : 0, kf1 = (f == XF - 1) ? 1 : 2;
    const int kh0 = (y == 0) ? 1 : 0, kh1 = (y == XH - 1) ? 1 : 2;

    // zero halo rows (w=-1 and w=128) of both buffers
    if (tid < 36) {
        const int b = tid / 18, rr = (tid % 18) / 9, k = tid % 9;
        const short8 zz = {0, 0, 0, 0, 0, 0, 0, 0};
        *(short8*)(&lds[b][(rr ? 129 * 72 : 0) + k * 8]) = zz;
    }

    const int scol = 1 + (tid >> 1);
    const int sic  = (tid & 1) * 32;

    // stage first B row-group into buffer 0
    {
        const unsigned short* s = xT + (size_t)((f + kf0 - 1) * 128 + (y + kh0 - 1)) * 8192
                                  + (tid >> 1) * 64 + sic;
        short8 v0 = *(const short8*)(s);
        short8 v1 = *(const short8*)(s + 8);
        short8 v2 = *(const short8*)(s + 16);
        short8 v3 = *(const short8*)(s + 24);
        unsigned short* d = &lds[0][scol * 72 + sic];
        *(short8*)(d) = v0; *(short8*)(d + 8) = v1;
        *(short8*)(d + 16) = v2; *(short8*)(d + 24) = v3;
    }
    __syncthreads();

    f32x4 acc[4][4];
#pragma unroll
    for (int mm = 0; mm < 4; ++mm)
#pragma unroll
        for (int nn = 0; nn < 4; ++nn) {
            f32x4 z = {0.f, 0.f, 0.f, 0.f};
            acc[mm][nn] = z;
        }

    int gi = 0;
#pragma unroll 1
    for (int kf = kf0; kf <= kf1; ++kf) {
#pragma unroll 1
        for (int kh = kh0; kh <= kh1; ++kh, ++gi) {
            const int cb = gi & 1;

            int nkf = kf, nkh = kh + 1;
            if (nkh > kh1) { nkf = kf + 1; nkh = kh0; }
            const bool hasNext = (nkf <= kf1);

            // T14: issue next B row-group loads early (hide under MFMAs)
            short8 pf0, pf1, pf2, pf3;
            if (hasNext) {
                const unsigned short* s = xT
                    + (size_t)((f + nkf - 1) * 128 + (y + nkh - 1)) * 8192
                    + (tid >> 1) * 64 + sic;
                pf0 = *(const short8*)(s);
                pf1 = *(const short8*)(s + 8);
                pf2 = *(const short8*)(s + 16);
                pf3 = *(const short8*)(s + 24);
            }

            const unsigned short* wt0 = Wb + (size_t)(kf * 3 + kh) * 3 * 16384;
#pragma unroll
            for (int kw = 0; kw < 3; ++kw) {
                const unsigned short* wt = wt0 + kw * 16384 + wmoff;
#pragma unroll
                for (int ks = 0; ks < 2; ++ks) {
                    short8 a[4], b[4];
#pragma unroll
                    for (int mm = 0; mm < 4; ++mm)
                        a[mm] = *(const short8*)(wt + mm * 1024 + ks * 32);
#pragma unroll
                    for (int nn = 0; nn < 4; ++nn) {
                        const int col = wn * 64 + nn * 16 + lr + kw;  // halo-shifted
                        b[nn] = *(const short8*)(&lds[cb][col * 72 + ks * 32 + lg * 8]);
                    }
#pragma unroll
                    for (int mm = 0; mm < 4; ++mm)
#pragma unroll
                        for (int nn = 0; nn < 4; ++nn)
                            acc[mm][nn] = __builtin_amdgcn_mfma_f32_16x16x32_bf16(
                                a[mm], b[nn], acc[mm][nn], 0, 0, 0);
                }
            }

            if (hasNext) {
                unsigned short* d = &lds[cb ^ 1][scol * 72 + sic];
                *(short8*)(d) = pf0; *(short8*)(d + 8) = pf1;
                *(short8*)(d + 16) = pf2; *(short8*)(d + 24) = pf3;
                __syncthreads();
            }
        }
    }

    // epilogue: bias + shuffle scatter + skip (verified algebra)
#pragma unroll
    for (int mm = 0; mm < 4; ++mm) {
        const int chb = chHalf * 128 + wm * 64 + mm * 16 + lg * 4;
#pragma unroll
        for (int nn = 0; nn < 4; ++nn) {
            const int wcol = wn * 64 + nn * 16 + lr;
#pragma unroll
            for (int r = 0; r < 4; ++r) {
                const int ch = chb + r;
                const float h = acc[mm][nn][r] + bias[ch];
                if (f == 0) {
                    if (ch & 32) continue;
                    const int p = ch >> 7, q = (ch >> 6) & 1, m = ch & 31;
                    const float sk = x[(size_t)((p * 64 + q * 32 + m) >> 1) * XCS
                                       + y * XWD + wcol];
                    out[(size_t)m * OCS + (size_t)(2 * y + p) * 256 + 2 * wcol + q]
                        = h + sk;
                } else {
                    const int aa = ch >> 7, p = (ch >> 6) & 1, q = (ch >> 5) & 1,
                              m = ch & 31;
                    const int fo = 1 + 2 * (f - 1) + aa;
                    const float sk = x[(size_t)(ch >> 2) * XCS
                                       + (size_t)f * (XH * XWD) + y * XWD + wcol];
                    out[(size_t)m * OCS + (size_t)fo * OFS
                        + (size_t)(2 * y + p) * 256 + 2 * wcol + q] = h + sk;
                }
            }
        }
    }
}

extern "C" void kernel_launch(void* const* d_in, const int* in_sizes, int n_in,
                              void* d_out, int out_size, void* d_ws, size_t ws_size,
                              hipStream_t stream) {
    const float* x  = (const float*)d_in[0];
    const float* Wf = (const float*)d_in[1];
    const float* b  = (const float*)d_in[2];
    float* out = (float*)d_out;

    unsigned short* Wb = (unsigned short*)d_ws;                         // 884,736 B
    unsigned short* xT = (unsigned short*)((char*)d_ws + (1 << 20));    // 35.65 MB

    prep_w<<<dim3(1728), dim3(256), 0, stream>>>(Wf, Wb);
    prep_x<<<dim3(17 * 128), dim3(256), 0, stream>>>(x, xT);
    conv_mfma<<<dim3(17 * 128 * 2), dim3(256), 0, stream>>>(x, Wb, b, xT, out);
}

// Round 13
// 719.572 us; speedup vs baseline: 1.3180x; 1.2520x over previous
//
#include <hip/hip_runtime.h>

// Round 13: A (weights) moved into LDS with per-tap ping-pong + XOR swizzle (T2),
// T14 reg-staging for both A and B. B single-buffered. Removes per-step global
// loads from the MFMA dependency chain (r7/r11/r12 showed MfmaUtil pinned at 15%
// by per-step L2 drain regardless of occupancy).

#define XF 17
#define XH 128
#define XWD 128
#define XCS (XF * XH * XWD)      // 278528
#define OCS (33 * 256 * 256)
#define OFS (256 * 256)

typedef short short8 __attribute__((ext_vector_type(8)));
typedef float f32x4 __attribute__((ext_vector_type(4)));

__device__ inline unsigned short f2bf(float v) {
    union { float f; unsigned u; } c; c.f = v;
    unsigned r = c.u + 0x7FFFu + ((c.u >> 16) & 1u);
    return (unsigned short)(r >> 16);
}

__global__ __launch_bounds__(256) void prep_w(const float* __restrict__ Wf,
                                              unsigned short* __restrict__ Wb) {
    const int idx = blockIdx.x * 256 + threadIdx.x;     // tap*16384 + ch*64 + ic
    const int ic = idx & 63, ch = (idx >> 6) & 255, t = idx >> 14;
    Wb[idx] = f2bf(Wf[(ch * 64 + ic) * 27 + t]);
}

__global__ __launch_bounds__(256) void prep_x(const float* __restrict__ x,
                                              unsigned short* __restrict__ xT) {
    __shared__ unsigned short l[128][72];
    const int f = blockIdx.x >> 7, y = blockIdx.x & 127;
    const int tid = threadIdx.x;
    const int w = tid & 127;
#pragma unroll
    for (int rep = 0; rep < 32; ++rep) {
        const int ic = rep * 2 + (tid >> 7);
        l[w][ic] = f2bf(x[(size_t)ic * XCS + f * (XH * XWD) + y * XWD + w]);
    }
    __syncthreads();
    unsigned short* dst = xT + (size_t)(f * 128 + y) * 8192;
    const int icg = tid & 7;
#pragma unroll
    for (int rep = 0; rep < 4; ++rep) {
        const int ww = rep * 32 + (tid >> 3);
        *(short8*)(dst + ww * 64 + icg * 8) = *(const short8*)(&l[ww][icg * 8]);
    }
}

// issue 4x16B reg loads of A-tap `tap` (per-thread 64B slice)
#define ISSUE_A(tap)                                                          \
    {                                                                         \
        const unsigned short* _s = wsrcBase + (size_t)(tap)*16384;            \
        sA0 = *(const short8*)(_s);                                           \
        sA1 = *(const short8*)(_s + 8);                                       \
        sA2 = *(const short8*)(_s + 16);                                      \
        sA3 = *(const short8*)(_s + 24);                                      \
    }

// swizzled ds_write of the staged slice into Alds[nb]
#define WRITE_A(nb)                                                           \
    {                                                                         \
        unsigned short* _d = &Alds[nb][sl * 64];                              \
        *(short8*)(_d + ((sjb + 0) ^ (sl & 7)) * 8) = sA0;                    \
        *(short8*)(_d + ((sjb + 1) ^ (sl & 7)) * 8) = sA1;                    \
        *(short8*)(_d + ((sjb + 2) ^ (sl & 7)) * 8) = sA2;                    \
        *(short8*)(_d + ((sjb + 3) ^ (sl & 7)) * 8) = sA3;                    \
    }

// one K32 half-step: A frags from swizzled Alds[curv], B frags from Blds
#define HALF_STEP(ksv, curv, kwv)                                             \
    {                                                                         \
        short8 a0, a1, a2, a3, b0, b1, b2, b3;                                \
        const unsigned short* _ab =                                           \
            &Alds[curv][(wm * 64 + lr) * 64 + ((((ksv)*4 + lg) ^ (lr & 7)) * 8)]; \
        a0 = *(const short8*)(_ab + 0 * 1024);                                \
        a1 = *(const short8*)(_ab + 1 * 1024);                                \
        a2 = *(const short8*)(_ab + 2 * 1024);                                \
        a3 = *(const short8*)(_ab + 3 * 1024);                                \
        b0 = *(const short8*)(&Blds[(wn * 64 + 0 + lr + (kwv)) * 72 + (ksv)*32 + lg * 8]);  \
        b1 = *(const short8*)(&Blds[(wn * 64 + 16 + lr + (kwv)) * 72 + (ksv)*32 + lg * 8]); \
        b2 = *(const short8*)(&Blds[(wn * 64 + 32 + lr + (kwv)) * 72 + (ksv)*32 + lg * 8]); \
        b3 = *(const short8*)(&Blds[(wn * 64 + 48 + lr + (kwv)) * 72 + (ksv)*32 + lg * 8]); \
        acc[0][0] = __builtin_amdgcn_mfma_f32_16x16x32_bf16(a0, b0, acc[0][0], 0, 0, 0); \
        acc[1][0] = __builtin_amdgcn_mfma_f32_16x16x32_bf16(a1, b0, acc[1][0], 0, 0, 0); \
        acc[2][0] = __builtin_amdgcn_mfma_f32_16x16x32_bf16(a2, b0, acc[2][0], 0, 0, 0); \
        acc[3][0] = __builtin_amdgcn_mfma_f32_16x16x32_bf16(a3, b0, acc[3][0], 0, 0, 0); \
        acc[0][1] = __builtin_amdgcn_mfma_f32_16x16x32_bf16(a0, b1, acc[0][1], 0, 0, 0); \
        acc[1][1] = __builtin_amdgcn_mfma_f32_16x16x32_bf16(a1, b1, acc[1][1], 0, 0, 0); \
        acc[2][1] = __builtin_amdgcn_mfma_f32_16x16x32_bf16(a2, b1, acc[2][1], 0, 0, 0); \
        acc[3][1] = __builtin_amdgcn_mfma_f32_16x16x32_bf16(a3, b1, acc[3][1], 0, 0, 0); \
        acc[0][2] = __builtin_amdgcn_mfma_f32_16x16x32_bf16(a0, b2, acc[0][2], 0, 0, 0); \
        acc[1][2] = __builtin_amdgcn_mfma_f32_16x16x32_bf16(a1, b2, acc[1][2], 0, 0, 0); \
        acc[2][2] = __builtin_amdgcn_mfma_f32_16x16x32_bf16(a2, b2, acc[2][2], 0, 0, 0); \
        acc[3][2] = __builtin_amdgcn_mfma_f32_16x16x32_bf16(a3, b2, acc[3][2], 0, 0, 0); \
        acc[0][3] = __builtin_amdgcn_mfma_f32_16x16x32_bf16(a0, b3, acc[0][3], 0, 0, 0); \
        acc[1][3] = __builtin_amdgcn_mfma_f32_16x16x32_bf16(a1, b3, acc[1][3], 0, 0, 0); \
        acc[2][3] = __builtin_amdgcn_mfma_f32_16x16x32_bf16(a2, b3, acc[2][3], 0, 0, 0); \
        acc[3][3] = __builtin_amdgcn_mfma_f32_16x16x32_bf16(a3, b3, acc[3][3], 0, 0, 0); \
    }

// block = (f, y, chHalf); 4 waves = 2M(64ch) x 2N(64w); tile 128ch x 128w
__global__ __launch_bounds__(256, 3) void conv_mfma(
    const float* __restrict__ x, const unsigned short* __restrict__ Wb,
    const float* __restrict__ bias, const unsigned short* __restrict__ xT,
    float* __restrict__ out)
{
    __shared__ __align__(16) unsigned short Alds[2][8192];  // 2 x 16KB, XOR-swizzled
    __shared__ __align__(16) unsigned short Blds[9360];     // 130 x 72 (pad+halo)

    const int tid = threadIdx.x;
    const int lane = tid & 63, lr = lane & 15, lg = lane >> 4;
    const int wv = tid >> 6, wm = wv >> 1, wn = wv & 1;

    // bijective XCD-chunked swizzle: 4352 blocks = 8 XCDs x 544
    const int bid = blockIdx.x;
    const int sbid = (bid & 7) * 544 + (bid >> 3);
    const int chHalf = sbid & 1;
    const int y = (sbid >> 1) & 127;
    const int f = sbid >> 8;

    const int kf0 = (f == 0) ? 1 : 0, kf1 = (f == XF - 1) ? 1 : 2;
    const int kh0 = (y == 0) ? 1 : 0, kh1 = (y == XH - 1) ? 1 : 2;

    // zero B halo rows (w=-1 and w=128)
    if (tid < 18) {
        const int rr = tid / 9, k = tid % 9;
        const short8 zz = {0, 0, 0, 0, 0, 0, 0, 0};
        *(short8*)(&Blds[(rr ? 129 * 72 : 0) + k * 8]) = zz;
    }

    // staging slots
    const int scol = 1 + (tid >> 1);        // B col (halo-shifted)
    const int sic  = (tid & 1) * 32;        // B ic offset (shorts)
    const int sl   = tid >> 1;              // A local row 0..127
    const int sjb  = (tid & 1) * 4;         // A 16B-chunk base (0 or 4)
    const unsigned short* wsrcBase = Wb + (size_t)(chHalf * 128 + sl) * 64 + sjb * 8;

    short8 sA0, sA1, sA2, sA3;

    // ---- prologue: stage B(first group) + A(first tap) ----
    {
        const unsigned short* s = xT + (size_t)((f + kf0 - 1) * 128 + (y + kh0 - 1)) * 8192
                                  + (tid >> 1) * 64 + sic;
        short8 v0 = *(const short8*)(s);
        short8 v1 = *(const short8*)(s + 8);
        short8 v2 = *(const short8*)(s + 16);
        short8 v3 = *(const short8*)(s + 24);
        ISSUE_A((kf0 * 3 + kh0) * 3);
        unsigned short* d = &Blds[scol * 72 + sic];
        *(short8*)(d) = v0; *(short8*)(d + 8) = v1;
        *(short8*)(d + 16) = v2; *(short8*)(d + 24) = v3;
        WRITE_A(0);
    }
    __syncthreads();

    f32x4 acc[4][4];
#pragma unroll
    for (int mm = 0; mm < 4; ++mm)
#pragma unroll
        for (int nn = 0; nn < 4; ++nn) {
            f32x4 z = {0.f, 0.f, 0.f, 0.f};
            acc[mm][nn] = z;
        }

    int cur = 0;
#pragma unroll 1
    for (int kf = kf0; kf <= kf1; ++kf) {
#pragma unroll 1
        for (int kh = kh0; kh <= kh1; ++kh) {
            int nkf = kf, nkh = kh + 1;
            if (nkh > kh1) { nkf = kf + 1; nkh = kh0; }
            const bool hasNext = (nkf <= kf1);
            const int tap0 = (kf * 3 + kh) * 3;

            // T14: issue next B row-group loads at group top (held in regs)
            short8 pf0, pf1, pf2, pf3;
            if (hasNext) {
                const unsigned short* s = xT
                    + (size_t)((f + nkf - 1) * 128 + (y + nkh - 1)) * 8192
                    + (tid >> 1) * 64 + sic;
                pf0 = *(const short8*)(s);
                pf1 = *(const short8*)(s + 8);
                pf2 = *(const short8*)(s + 16);
                pf3 = *(const short8*)(s + 24);
            }

#pragma unroll
            for (int kw = 0; kw < 3; ++kw) {
                const bool stage = (kw < 2) || hasNext;
                const int tapN = (kw < 2) ? (tap0 + kw + 1) : ((nkf * 3 + nkh) * 3);
                if (stage) ISSUE_A(tapN);
                HALF_STEP(0, cur, kw);
                if (stage) WRITE_A(cur ^ 1);     // overlaps ks=1 compute
                HALF_STEP(1, cur, kw);
                if (kw == 2) {
                    if (hasNext) {
                        __syncthreads();          // A(next t0) visible; B reads done
                        unsigned short* d = &Blds[scol * 72 + sic];
                        *(short8*)(d) = pf0; *(short8*)(d + 8) = pf1;
                        *(short8*)(d + 16) = pf2; *(short8*)(d + 24) = pf3;
                        __syncthreads();          // B(next) visible
                    }
                } else {
                    __syncthreads();              // A(t+1) visible
                }
                if (stage) cur ^= 1;
            }
        }
    }

    // ---- epilogue: bias + shuffle scatter + skip (verified algebra) ----
#pragma unroll
    for (int mm = 0; mm < 4; ++mm) {
        const int chb = chHalf * 128 + wm * 64 + mm * 16 + lg * 4;
#pragma unroll
        for (int nn = 0; nn < 4; ++nn) {
            const int wcol = wn * 64 + nn * 16 + lr;
#pragma unroll
            for (int r = 0; r < 4; ++r) {
                const int ch = chb + r;
                const float h = acc[mm][nn][r] + bias[ch];
                if (f == 0) {
                    if (ch & 32) continue;
                    const int p = ch >> 7, q = (ch >> 6) & 1, m = ch & 31;
                    const float sk = x[(size_t)((p * 64 + q * 32 + m) >> 1) * XCS
                                       + y * XWD + wcol];
                    out[(size_t)m * OCS + (size_t)(2 * y + p) * 256 + 2 * wcol + q]
                        = h + sk;
                } else {
                    const int aa = ch >> 7, p = (ch >> 6) & 1, q = (ch >> 5) & 1,
                              m = ch & 31;
                    const int fo = 1 + 2 * (f - 1) + aa;
                    const float sk = x[(size_t)(ch >> 2) * XCS
                                       + (size_t)f * (XH * XWD) + y * XWD + wcol];
                    out[(size_t)m * OCS + (size_t)fo * OFS
                        + (size_t)(2 * y + p) * 256 + 2 * wcol + q] = h + sk;
                }
            }
        }
    }
}

extern "C" void kernel_launch(void* const* d_in, const int* in_sizes, int n_in,
                              void* d_out, int out_size, void* d_ws, size_t ws_size,
                              hipStream_t stream) {
    const float* x  = (const float*)d_in[0];
    const float* Wf = (const float*)d_in[1];
    const float* b  = (const float*)d_in[2];
    float* out = (float*)d_out;

    unsigned short* Wb = (unsigned short*)d_ws;                         // 884,736 B
    unsigned short* xT = (unsigned short*)((char*)d_ws + (1 << 20));    // 35.65 MB

    prep_w<<<dim3(1728), dim3(256), 0, stream>>>(Wf, Wb);
    prep_x<<<dim3(17 * 128), dim3(256), 0, stream>>>(x, xT);
    conv_mfma<<<dim3(17 * 128 * 2), dim3(256), 0, stream>>>(x, Wb, b, xT, out);
}